// Round 1
// baseline (1063.228 us; speedup 1.0000x reference)
//
#include <hip/hip_runtime.h>
#include <hip/hip_bf16.h>

// Euclidean cdist: out[b,j] = ||x[b,:] - w[:,j]||, B=4096 D=64 K=50000, fp32.
// Strategy: bf16 MFMA for the x@w GEMM (write-bound, ~130us floor on 819MB
// output), fp32 epilogue sqrt(x2 + w2 - 2xw). Norms computed from the SAME
// bf16-rounded values so result == ||x~ - w~|| exactly (fp32 accum).

typedef __bf16 bf16x8 __attribute__((ext_vector_type(8)));
typedef float floatx4 __attribute__((ext_vector_type(4)));
typedef float float4v __attribute__((ext_vector_type(4)));
typedef unsigned short ushortx4 __attribute__((ext_vector_type(4)));
typedef unsigned short ushortx8 __attribute__((ext_vector_type(8)));
typedef short short8 __attribute__((ext_vector_type(8)));

constexpr int Bb = 4096;
constexpr int Dd = 64;
constexpr int Kk = 50000;
constexpr int BM = 128;
constexpr int BN = 128;
constexpr int LDA = 72;  // bf16 elems per LDS row (64 + 8 pad -> 2-way bank alias = free)

__device__ __forceinline__ unsigned short f2bf(float f) {
  union { float f; unsigned u; } v; v.f = f;
  unsigned r = v.u + 0x7FFFu + ((v.u >> 16) & 1u);  // round-to-nearest-even
  return (unsigned short)(r >> 16);
}
__device__ __forceinline__ float bf2f(unsigned short h) {
  union { unsigned u; float f; } v; v.u = ((unsigned)h) << 16;
  return v.f;
}

__global__ void euclid_kernel(const float* __restrict__ x,
                              const float* __restrict__ w,
                              float* __restrict__ out) {
  __shared__ alignas(16) unsigned short As[BM * LDA];  // A[row][k] bf16
  __shared__ alignas(16) unsigned short Bs[BN * LDA];  // B^T[col][k] bf16
  __shared__ float x2s[BM];
  __shared__ float w2s[BN];

  const int tid = threadIdx.x;
  const int m0 = blockIdx.x * BM;   // 32 row tiles (x-fastest: shares w-tile in L2)
  const int j0 = blockIdx.y * BN;   // 391 col tiles

  // ---- stage A: x[m0:m0+128][0:64] fp32 -> bf16 LDS ----
  {
    const float4v* x4 = (const float4v*)(x + (size_t)m0 * Dd);
#pragma unroll
    for (int it = 0; it < (BM * Dd / 4) / 256; ++it) {  // 8 iters
      int i = it * 256 + tid;
      float4v v = x4[i];
      int r = i >> 4;   // 16 float4 per row
      int q = i & 15;
      ushortx4 h;
      h.x = f2bf(v.x); h.y = f2bf(v.y); h.z = f2bf(v.z); h.w = f2bf(v.w);
      *(ushortx4*)&As[r * LDA + q * 4] = h;
    }
  }

  // ---- stage B: w[0:64][j0:j0+128] fp32 -> bf16 LDS, transposed ----
  {
    int c = tid & 127;
    int gc = j0 + c;
    bool valid = gc < Kk;
    const float* wp = w + gc;
#pragma unroll
    for (int k = (tid >> 7) * 2; k < Dd; k += 4) {
      float v0 = valid ? wp[(size_t)k * Kk] : 0.0f;
      float v1 = valid ? wp[(size_t)(k + 1) * Kk] : 0.0f;
      unsigned pack = (unsigned)f2bf(v0) | ((unsigned)f2bf(v1) << 16);
      *(unsigned*)&Bs[c * LDA + k] = pack;  // 4B aligned (144c + 2k, k even)
    }
  }
  __syncthreads();

  // ---- per-tile norms from the bf16-rounded values ----
  if (tid < BM) {
    float s = 0.f;
#pragma unroll
    for (int kq = 0; kq < 8; ++kq) {
      ushortx8 u = *(const ushortx8*)&As[tid * LDA + kq * 8];
#pragma unroll
      for (int j = 0; j < 8; ++j) { float v = bf2f(u[j]); s = fmaf(v, v, s); }
    }
    x2s[tid] = s;
  } else {
    int c = tid - BM;
    float s = 0.f;
#pragma unroll
    for (int kq = 0; kq < 8; ++kq) {
      ushortx8 u = *(const ushortx8*)&Bs[c * LDA + kq * 8];
#pragma unroll
      for (int j = 0; j < 8; ++j) { float v = bf2f(u[j]); s = fmaf(v, v, s); }
    }
    w2s[c] = s;
  }
  __syncthreads();

  // ---- MFMA compute: each wave does rows [32w, 32w+32) x cols [0,128) ----
  const int wv = tid >> 6;
  const int lane = tid & 63;
  const int l15 = lane & 15;
  const int quad = lane >> 4;

  bf16x8 a[2][2];
#pragma unroll
  for (int mi = 0; mi < 2; ++mi)
#pragma unroll
    for (int kc = 0; kc < 2; ++kc)
      a[mi][kc] = *(const bf16x8*)&As[(32 * wv + 16 * mi + l15) * LDA + kc * 32 + quad * 8];

  floatx4 acc[2][8];
#pragma unroll
  for (int mi = 0; mi < 2; ++mi)
#pragma unroll
    for (int ni = 0; ni < 8; ++ni)
      acc[mi][ni] = (floatx4){0.f, 0.f, 0.f, 0.f};

#pragma unroll
  for (int ni = 0; ni < 8; ++ni) {
    bf16x8 b0 = *(const bf16x8*)&Bs[(16 * ni + l15) * LDA + quad * 8];
    bf16x8 b1 = *(const bf16x8*)&Bs[(16 * ni + l15) * LDA + 32 + quad * 8];
#pragma unroll
    for (int mi = 0; mi < 2; ++mi) {
      acc[mi][ni] = __builtin_amdgcn_mfma_f32_16x16x32_bf16(a[mi][0], b0, acc[mi][ni], 0, 0, 0);
      acc[mi][ni] = __builtin_amdgcn_mfma_f32_16x16x32_bf16(a[mi][1], b1, acc[mi][ni], 0, 0, 0);
    }
  }

  // ---- epilogue: sqrt(max(x2 + w2 - 2xw, eps)), guarded stores ----
  // C/D layout (m89-verified): col = lane&15, row = quad*4 + reg
  float xn[2][4];
#pragma unroll
  for (int mi = 0; mi < 2; ++mi)
#pragma unroll
    for (int r = 0; r < 4; ++r)
      xn[mi][r] = x2s[32 * wv + 16 * mi + quad * 4 + r];

#pragma unroll
  for (int ni = 0; ni < 8; ++ni) {
    int col = 16 * ni + l15;
    int gcol = j0 + col;
    if (gcol >= Kk) continue;
    float w2 = w2s[col];
#pragma unroll
    for (int mi = 0; mi < 2; ++mi) {
      int rbase = 32 * wv + 16 * mi + quad * 4;
#pragma unroll
      for (int r = 0; r < 4; ++r) {
        float sq = xn[mi][r] + w2 - 2.0f * acc[mi][ni][r];
        sq = fmaxf(sq, 1e-12f);
        out[(size_t)(m0 + rbase + r) * Kk + gcol] = sqrtf(sq);
      }
    }
  }
}

extern "C" void kernel_launch(void* const* d_in, const int* in_sizes, int n_in,
                              void* d_out, int out_size, void* d_ws, size_t ws_size,
                              hipStream_t stream) {
  const float* x = (const float*)d_in[0];
  const float* w = (const float*)d_in[1];
  float* out = (float*)d_out;
  dim3 grid(Bb / BM, (Kk + BN - 1) / BN);  // (32, 391)
  euclid_kernel<<<grid, dim3(256), 0, stream>>>(x, w, out);
}